// Round 14
// baseline (320.834 us; speedup 1.0000x reference)
//
#include <hip/hip_runtime.h>
#include <hip/hip_bf16.h>
#include <hip/hip_fp16.h>

#define NG 32
#define NH 16
#define NR 15
#define HS 256
#define NT 1000
#define NS 2000
#define LOUT (NT - NR + 1)  // 986
#define TC 40               // scan time-chunk
#define SPB 8               // scan sites per block
#define NCH (NT / TC)       // 25 chunks
#define NTP 1001            // padded sQ row (bank-conflict break)
#define SSB 4               // k_site sites per block

typedef __attribute__((ext_vector_type(8))) short bhalf8;
typedef __attribute__((ext_vector_type(4))) float f32x4;
typedef __attribute__((ext_vector_type(2))) float f32x2;
typedef __attribute__((ext_vector_type(4))) unsigned short us4;
typedef __attribute__((ext_vector_type(8))) unsigned short us8;

__device__ __forceinline__ float fast_rcp(float x) { return __builtin_amdgcn_rcpf(x); }
__device__ __forceinline__ float fast_tanh(float x) {
    float e = __expf(2.0f * x);
    return 1.0f - 2.0f * fast_rcp(e + 1.0f);
}
__device__ __forceinline__ float fast_sigmoid(float x) {
    return fast_rcp(1.0f + __expf(-x));
}
__device__ __forceinline__ short f2bf(float f) {
    __bf16 h = (__bf16)f;
    return __builtin_bit_cast(short, h);
}
__device__ __forceinline__ float h2f(unsigned short u) {
    return (float)__builtin_bit_cast(_Float16, u);
}
__device__ __forceinline__ unsigned short f2h(float f) {
    return __builtin_bit_cast(unsigned short, (_Float16)f);
}

// ---------------------------------------------------------------------------
// Kernel 0: transpose x[t][s][6] -> 6 planes xT[s][p][t]
// ---------------------------------------------------------------------------
__global__ __launch_bounds__(256) void k_prep(const float* __restrict__ x,
                                              float* __restrict__ xT) {
    int s0 = blockIdx.x * 16;
    int t0 = blockIdx.y * 64;
    int tid = threadIdx.x;
    __shared__ float sX[64][97];
    for (int g = tid; g < 64 * 24; g += 256) {
        int tl = g / 24, c4 = g - tl * 24;
        if (t0 + tl < NT) {
            float4 v = *(const float4*)(x + ((size_t)(t0 + tl) * NS + s0) * 6 + c4 * 4);
            sX[tl][c4 * 4 + 0] = v.x;
            sX[tl][c4 * 4 + 1] = v.y;
            sX[tl][c4 * 4 + 2] = v.z;
            sX[tl][c4 * 4 + 3] = v.w;
        }
    }
    __syncthreads();
    int tl = tid & 63;
    int t = t0 + tl;
    if (t < NT) {
#pragma unroll
        for (int p = 0; p < 4; ++p) {
            int sl = (tid >> 6) + p * 4;
            const float* r = &sX[tl][sl * 6];
            size_t base = ((size_t)(s0 + sl) * 6) * NT + t;
            xT[base + 0 * NT] = r[0];
            xT[base + 1 * NT] = r[1];
            xT[base + 2 * NT] = r[2];
            xT[base + 3 * NT] = r[3];
            xT[base + 4 * NT] = r[4];
            xT[base + 5 * NT] = r[5];
        }
    }
}

// ---------------------------------------------------------------------------
// Kernel 1: per-site parameters, 4 sites per block — round-13 measured-good.
// ---------------------------------------------------------------------------
__global__ __launch_bounds__(256) void k_site(
    const float* __restrict__ xc, const float* __restrict__ W_fc, const float* __restrict__ b_fc,
    const float* __restrict__ W_r, const float* __restrict__ b_r,
    const float* __restrict__ W_g, const float* __restrict__ b_g,
    const float* __restrict__ b_kin,
    float* __restrict__ state2, float* __restrict__ params, float* __restrict__ wfir)
{
    int s0 = blockIdx.x * SSB, tid = threadIdx.x;
    __shared__ float sXc[SSB][NG];
    __shared__ float sG[SSB][HS];
    __shared__ float sPG[144][SSB];
    __shared__ float sPR[256][SSB];
    if (tid < SSB * NG) sXc[tid >> 5][tid & 31] = xc[(s0 + (tid >> 5)) * NG + (tid & 31)];
    __syncthreads();
    {
        float b = b_fc[tid];
        float a[SSB];
#pragma unroll
        for (int sl = 0; sl < SSB; ++sl) a[sl] = b;
#pragma unroll 8
        for (int g = 0; g < NG; ++g) {
            float w = W_fc[g * HS + tid];
#pragma unroll
            for (int sl = 0; sl < SSB; ++sl) a[sl] += sXc[sl][g] * w;
        }
        float bk = b_kin[tid];
#pragma unroll
        for (int sl = 0; sl < SSB; ++sl) {
            state2[(size_t)(s0 + sl) * HS + tid] = a[sl] + bk;
            sG[sl][tid] = fast_tanh(a[sl]);
        }
    }
    __syncthreads();
    {
        float b = b_r[tid];
        float r[SSB];
#pragma unroll
        for (int sl = 0; sl < SSB; ++sl) r[sl] = b;
#pragma unroll 8
        for (int u = 0; u < HS; ++u) {
            float w = W_r[u * 256 + tid];
#pragma unroll
            for (int sl = 0; sl < SSB; ++sl) r[sl] += sG[sl][u] * w;
        }
#pragma unroll
        for (int sl = 0; sl < SSB; ++sl) sPR[tid][sl] = r[sl];
    }
    if (tid < 144) {
        float b = b_g[tid];
        float gacc[SSB];
#pragma unroll
        for (int sl = 0; sl < SSB; ++sl) gacc[sl] = b;
#pragma unroll 8
        for (int u = 0; u < HS; ++u) {
            float w = W_g[u * 144 + tid];
#pragma unroll
            for (int sl = 0; sl < SSB; ++sl) gacc[sl] += sG[sl][u] * w;
        }
#pragma unroll
        for (int sl = 0; sl < SSB; ++sl) sPG[tid][sl] = gacc[sl];
    }
    __syncthreads();
    if (tid < SSB * NH) {
        int sl = tid >> 4, h = tid & 15;
        int s = s0 + sl;
        float m = -1e30f;
        for (int k = 0; k < NH; ++k) m = fmaxf(m, sPG[96 + k][sl]);
        float sum = 0.f;
        for (int k = 0; k < NH; ++k) sum += __expf(sPG[96 + k][sl] - m);
        float ga = __expf(sPG[96 + h][sl] - m) * fast_rcp(sum);
        float kp = fast_sigmoid(sPG[h][sl]);
        float ks = fast_sigmoid(sPG[16 + h][sl]);
        float kd = fast_sigmoid(sPG[32 + h][sl]);
        float gd = fast_sigmoid(sPG[48 + h][sl]);
        float glv = fast_sigmoid(sPG[64 + h][sl]) * 10.0f;
        float gl = glv * glv * glv;
        float qb = fmaxf(sPG[80 + h][sl], 0.f) * 0.1f;
        float gi = fminf(fmaxf(sPG[112 + h][sl] * (1.0f / 6.0f) + 0.5f, 0.f), 1.f) * 0.5f;
        float ge = fmaxf(sPG[128 + h][sl], 0.f);
        float* P = params + (size_t)s * 128;
        P[0 * 16 + h] = kp;  P[1 * 16 + h] = ks;  P[2 * 16 + h] = kd;  P[3 * 16 + h] = gd;
        P[4 * 16 + h] = gl;  P[5 * 16 + h] = qb;  P[6 * 16 + h] = gi;  P[7 * 16 + h] = ge;
        float loc = fast_sigmoid(sPR[h * 16 + 0][sl]) * 15.0f;
        float l[NR];
        float mm = -1e30f;
#pragma unroll
        for (int i = 0; i < NR; ++i) {
            float d = (float)i - loc;
            l[i] = sPR[h * 16 + 1 + i][sl] - d * d;
            mm = fmaxf(mm, l[i]);
        }
        float ssum = 0.f;
#pragma unroll
        for (int i = 0; i < NR; ++i) { l[i] = __expf(l[i] - mm); ssum += l[i]; }
        float r = fast_rcp(ssum) * ga;
#pragma unroll
        for (int i = 0; i < NR; ++i) wfir[(size_t)s * (NR * NH) + i * NH + h] = l[i] * r;
    }
}

// ---------------------------------------------------------------------------
// Kernel 2 (MFMA, split-K, packed-fp32, colsum trick) — round-8 math,
// SINGLE-buffered sRed (16 KB, 2 barriers/supergroup): LDS 33.8->17.4 KB
// lifts blocks/CU 4->6 (VGPR-limited) to fill trans-latency stalls.
// ---------------------------------------------------------------------------
__global__ __launch_bounds__(256) void k_km(
    const float* __restrict__ xT, const float* __restrict__ state2,
    const float* __restrict__ W_kin, const float* __restrict__ W_kout,
    const float* __restrict__ b_kout, _Float16* __restrict__ kmh)
{
    const float Ck = 2.8853900817779268f;  // 2*log2(e)
    int s = blockIdx.x, tid = threadIdx.x;
    int wave = tid >> 6, lane = tid & 63;
    int r15 = lane & 15, kg = lane >> 4;

    f32x2 st[2][4], w0[2][4], w1[2][4], w2[2][4], w3[2][4];
    bhalf8 Bf[2];
    float csp = 0.f;
#pragma unroll
    for (int q = 0; q < 2; ++q) {
        int u0 = (2 * wave + q) * 32 + kg * 8;
#pragma unroll
        for (int e = 0; e < 4; ++e) {
            int u = u0 + 2 * e;
            st[q][e] = *(const f32x2*)(state2 + s * HS + u) * Ck;
            w0[q][e] = *(const f32x2*)(W_kin + 0 * HS + u) * Ck;
            w1[q][e] = *(const f32x2*)(W_kin + 1 * HS + u) * Ck;
            w2[q][e] = *(const f32x2*)(W_kin + 2 * HS + u) * Ck;
            w3[q][e] = *(const f32x2*)(W_kin + 3 * HS + u) * Ck;
            float wa = W_kout[(u)     * NH + r15];
            float wb = W_kout[(u + 1) * NH + r15];
            csp += wa + wb;
            Bf[q][2 * e]     = f2bf(-2.0f * wa);
            Bf[q][2 * e + 1] = f2bf(-2.0f * wb);
        }
    }
    __shared__ float sCS[4][4][16];
    sCS[wave][kg][r15] = csp;
    __syncthreads();
    float bk2 = b_kout[r15];
#pragma unroll
    for (int w = 0; w < 4; ++w)
#pragma unroll
        for (int k = 0; k < 4; ++k) bk2 += sCS[w][k][r15];

    const float* fpl = xT + ((size_t)s * 6 + 2) * NT;
    _Float16* kp = kmh + (size_t)s * NT * NH;

    __shared__ f32x4 sRed[4][4][64];  // [tile][wave][lane], 16 KB

    for (int tg = 0; tg < 16; ++tg) {
#pragma unroll
        for (int tile = 0; tile < 4; ++tile) {
            int t = tg * 64 + tile * 16 + r15;
            int tcl = t < NT ? t : NT - 1;
            float f0 = fpl[tcl];
            float f1 = fpl[NT + tcl];
            float f2 = fpl[2 * NT + tcl];
            float f3 = fpl[3 * NT + tcl];
            f32x4 acc = {0.f, 0.f, 0.f, 0.f};
#pragma unroll
            for (int q = 0; q < 2; ++q) {
                bhalf8 A;
#pragma unroll
                for (int e = 0; e < 4; ++e) {
                    f32x2 p = st[q][e];
                    p += f0 * w0[q][e];
                    p += f1 * w1[q][e];
                    p += f2 * w2[q][e];
                    p += f3 * w3[q][e];
                    f32x2 ex = {__builtin_amdgcn_exp2f(p.x), __builtin_amdgcn_exp2f(p.y)};
                    f32x2 e1 = ex + 1.0f;
                    A[2 * e]     = f2bf(fast_rcp(e1.x));
                    A[2 * e + 1] = f2bf(fast_rcp(e1.y));
                }
                acc = __builtin_amdgcn_mfma_f32_16x16x32_bf16(A, Bf[q], acc, 0, 0, 0);
            }
            sRed[tile][wave][lane] = acc;
        }
        __syncthreads();
        {
            f32x4 a0 = sRed[wave][0][lane];
            f32x4 a1 = sRed[wave][1][lane];
            f32x4 a2 = sRed[wave][2][lane];
            f32x4 a3 = sRed[wave][3][lane];
            f32x4 acc = (a0 + a1) + (a2 + a3);
            int tb = tg * 64 + wave * 16;
#pragma unroll
            for (int j = 0; j < 4; ++j) {
                int tt = tb + kg * 4 + j;
                if (tt < NT) kp[(size_t)tt * NH + r15] = (_Float16)__expf(acc[j] + bk2);
            }
        }
        __syncthreads();  // WAR: protect sRed before next supergroup's writes
    }
}

// ---------------------------------------------------------------------------
// Kernel 3: sequential scan — round-4 direct-store version (measured best).
// ---------------------------------------------------------------------------
__global__ __launch_bounds__(128) void k_scan(
    const float* __restrict__ params, const float* __restrict__ xT,
    _Float16* __restrict__ kmh)
{
    int tid = threadIdx.x;
    int sl = tid >> 4, h = tid & 15;
    int S0 = blockIdx.x * SPB;
    __shared__ __align__(16) unsigned short sKmH[2][TC][128];
    __shared__ __align__(16) float sF[2][3][SPB][TC];

    const float* P = params + (size_t)(S0 + sl) * 128;
    float kp = P[h], ks = P[16 + h], kd = P[32 + h], gd = P[48 + h];
    float gl = P[64 + h], qb = P[80 + h], gi = P[96 + h], ge = P[112 + h];
    float gi1 = 1.f - gi, gd1 = 1.f - gd, kd1 = 1.f - kd;
    float Sf = 0.f, Ss = 0.f, Sd = 0.f;

    us4 vkm[10];
    float4 fP, fE, fT1, fT2;
    int fsite = tid / 10, ftcq = tid - fsite * 10;
    size_t fbase = ((size_t)(S0 + (fsite < SPB ? fsite : 0)) * 6) * NT + ftcq * 4;

    auto LOAD = [&](int t0) {
#pragma unroll
        for (int r = 0; r < 10; ++r) {
            int g = r * 128 + tid;
            int site = g / 160;
            int rem = g - site * 160;
            int tc = rem >> 2, h0 = (rem & 3) << 2;
            vkm[r] = *(const us4*)(kmh + (((size_t)(S0 + site) * NT + t0 + tc) * NH + h0));
        }
        if (tid < 80) {
            fP  = *(const float4*)(xT + fbase + t0);
            fE  = *(const float4*)(xT + fbase + (size_t)NT + t0);
            fT1 = *(const float4*)(xT + fbase + 2 * (size_t)NT + t0);
            fT2 = *(const float4*)(xT + fbase + 3 * (size_t)NT + t0);
        }
    };
    auto STORE_LDS = [&](int b) {
#pragma unroll
        for (int r = 0; r < 10; ++r) {
            int g = r * 128 + tid;
            int site = g / 160;
            int rem = g - site * 160;
            int tc = rem >> 2, h0 = (rem & 3) << 2;
            *(us4*)&sKmH[b][tc][site * 16 + h0] = vkm[r];
        }
        if (tid < 80) {
            float4 ps, pl;
            {
                float den = fmaxf(fT2.x - fT1.x, 1e-6f);
                float vL = fminf(fmaxf(fT2.x * fast_rcp(den), 0.f), 1.f);
                pl.x = fP.x * vL; ps.x = fP.x - pl.x;
            }
            {
                float den = fmaxf(fT2.y - fT1.y, 1e-6f);
                float vL = fminf(fmaxf(fT2.y * fast_rcp(den), 0.f), 1.f);
                pl.y = fP.y * vL; ps.y = fP.y - pl.y;
            }
            {
                float den = fmaxf(fT2.z - fT1.z, 1e-6f);
                float vL = fminf(fmaxf(fT2.z * fast_rcp(den), 0.f), 1.f);
                pl.z = fP.z * vL; ps.z = fP.z - pl.z;
            }
            {
                float den = fmaxf(fT2.w - fT1.w, 1e-6f);
                float vL = fminf(fmaxf(fT2.w * fast_rcp(den), 0.f), 1.f);
                pl.w = fP.w * vL; ps.w = fP.w - pl.w;
            }
            *(float4*)&sF[b][0][fsite][ftcq * 4] = ps;
            *(float4*)&sF[b][1][fsite][ftcq * 4] = pl;
            *(float4*)&sF[b][2][fsite][ftcq * 4] = fE;
        }
    };

    size_t qbase = ((size_t)(S0 + sl) * NT) * NH + h;

    LOAD(0);
    STORE_LDS(0);
    __syncthreads();
    for (int c = 0; c < NCH; ++c) {
        int b = c & 1;
        if (c + 1 < NCH) LOAD((c + 1) * TC);
        int t0 = c * TC;
#pragma unroll 8
        for (int tc = 0; tc < TC; ++tc) {
            float ps = sF[b][0][sl][tc], pl = sF[b][1][sl][tc], ev = sF[b][2][sl][tc];
            float kmv = h2f(sKmH[b][tc][tid]);
            Sf += ps;
            float qf = fminf(Sf, kmv);
            Sf -= qf;
            float Pin = pl + qf;
            float H = fmaxf(Ss + Pin * gi1 - ev * ge, 0.f);
            float qp = fmaxf(H - gl, 0.f) * kp;
            float qo = fminf(H, gl) * ks;
            Ss = H - qp - qo;
            float D = Sd + Pin * gi + qo * gd;
            float qd = D * kd + qb;
            Sd = D * kd1;
            kmh[qbase + (size_t)(t0 + tc) * NH] = (_Float16)(qp + qo * gd1 + qd);
        }
        if (c + 1 < NCH) {
            STORE_LDS((c + 1) & 1);
            __syncthreads();
        }
    }
}

// ---------------------------------------------------------------------------
// Kernel 4: FIR readout — round-13 version (direct scattered store).
// ---------------------------------------------------------------------------
__global__ __launch_bounds__(256) void k_fir(
    const _Float16* __restrict__ kmh, const float* __restrict__ wfir,
    float* __restrict__ out)
{
    int s = blockIdx.x, tid = threadIdx.x;
    __shared__ float sQ[NH * NTP];
    __shared__ float sW[NR * NH];
    const us8* src = (const us8*)(kmh + (size_t)s * NT * NH);
    for (int g = tid; g < NT * NH / 8; g += 256) {
        us8 v = src[g];
        int t = g >> 1, h0 = (g & 1) << 3;
#pragma unroll
        for (int e = 0; e < 8; ++e)
            sQ[(h0 + e) * NTP + t] = h2f(v[e]);
    }
    if (tid < NR * NH) sW[tid] = wfir[(size_t)s * NR * NH + tid];
    __syncthreads();
#pragma unroll
    for (int c = 0; c < 4; ++c) {
        int tau = tid + 256 * c;
        if (tau < LOUT) {
            float acc = 0.f;
#pragma unroll
            for (int hh = 0; hh < NH; ++hh) {
                const float* q = sQ + hh * NTP + tau;
#pragma unroll
                for (int i = 0; i < NR; ++i) acc += q[i] * sW[i * 16 + hh];
            }
            out[(size_t)tau * NS + s] = acc;
        }
    }
}

// ---------------------------------------------------------------------------
extern "C" void kernel_launch(void* const* d_in, const int* in_sizes, int n_in,
                              void* d_out, int out_size, void* d_ws, size_t ws_size,
                              hipStream_t stream) {
    const float* x      = (const float*)d_in[0];
    const float* xc     = (const float*)d_in[1];
    const float* W_fc   = (const float*)d_in[2];
    const float* b_fc   = (const float*)d_in[3];
    const float* W_r    = (const float*)d_in[4];
    const float* b_r    = (const float*)d_in[5];
    const float* W_g    = (const float*)d_in[6];
    const float* b_g    = (const float*)d_in[7];
    const float* W_kin  = (const float*)d_in[8];
    const float* b_kin  = (const float*)d_in[9];
    const float* W_kout = (const float*)d_in[10];
    const float* b_kout = (const float*)d_in[11];
    float* out = (float*)d_out;

    float* ws     = (float*)d_ws;
    float* state2 = ws;                             // NS*HS
    float* params = state2 + (size_t)NS * HS;       // NS*128
    float* wfir   = params + (size_t)NS * 128;      // NS*NR*NH
    float* xT     = wfir + (size_t)NS * NR * NH;    // NS*6*NT
    _Float16* kmh = (_Float16*)(xT + (size_t)NS * 6 * NT);   // NS*NT*NH fp16

    k_prep<<<dim3(NS / 16, (NT + 63) / 64), 256, 0, stream>>>(x, xT);
    k_site<<<NS / SSB, 256, 0, stream>>>(xc, W_fc, b_fc, W_r, b_r, W_g, b_g, b_kin,
                                         state2, params, wfir);
    k_km<<<NS, 256, 0, stream>>>(xT, state2, W_kin, W_kout, b_kout, kmh);
    k_scan<<<NS / SPB, 128, 0, stream>>>(params, xT, kmh);
    k_fir<<<NS, 256, 0, stream>>>(kmh, wfir, out);
}

// Round 15
// 285.534 us; speedup vs baseline: 1.1236x; 1.1236x over previous
//
#include <hip/hip_runtime.h>
#include <hip/hip_bf16.h>
#include <hip/hip_fp16.h>

#define NG 32
#define NH 16
#define NR 15
#define HS 256
#define NT 1000
#define NS 2000
#define LOUT (NT - NR + 1)  // 986
#define TC 40               // scan time-chunk
#define SPB 8               // scan sites per block
#define NCH (NT / TC)       // 25 chunks
#define SSB 4               // k_site sites per block
#define QROW 1048           // k_fir fp16 row (tail-zeroed, 8B-aligned rows)

typedef __attribute__((ext_vector_type(8))) short bhalf8;
typedef __attribute__((ext_vector_type(4))) float f32x4;
typedef __attribute__((ext_vector_type(2))) float f32x2;
typedef __attribute__((ext_vector_type(4))) unsigned short us4;
typedef __attribute__((ext_vector_type(8))) unsigned short us8;

__device__ __forceinline__ float fast_rcp(float x) { return __builtin_amdgcn_rcpf(x); }
__device__ __forceinline__ float fast_tanh(float x) {
    float e = __expf(2.0f * x);
    return 1.0f - 2.0f * fast_rcp(e + 1.0f);
}
__device__ __forceinline__ float fast_sigmoid(float x) {
    return fast_rcp(1.0f + __expf(-x));
}
__device__ __forceinline__ short f2bf(float f) {
    __bf16 h = (__bf16)f;
    return __builtin_bit_cast(short, h);
}
__device__ __forceinline__ float h2f(unsigned short u) {
    return (float)__builtin_bit_cast(_Float16, u);
}
__device__ __forceinline__ unsigned short f2h(float f) {
    return __builtin_bit_cast(unsigned short, (_Float16)f);
}

// ---------------------------------------------------------------------------
// Kernel 0: transpose x[t][s][6] -> 6 planes xT[s][p][t]
// ---------------------------------------------------------------------------
__global__ __launch_bounds__(256) void k_prep(const float* __restrict__ x,
                                              float* __restrict__ xT) {
    int s0 = blockIdx.x * 16;
    int t0 = blockIdx.y * 64;
    int tid = threadIdx.x;
    __shared__ float sX[64][97];
    for (int g = tid; g < 64 * 24; g += 256) {
        int tl = g / 24, c4 = g - tl * 24;
        if (t0 + tl < NT) {
            float4 v = *(const float4*)(x + ((size_t)(t0 + tl) * NS + s0) * 6 + c4 * 4);
            sX[tl][c4 * 4 + 0] = v.x;
            sX[tl][c4 * 4 + 1] = v.y;
            sX[tl][c4 * 4 + 2] = v.z;
            sX[tl][c4 * 4 + 3] = v.w;
        }
    }
    __syncthreads();
    int tl = tid & 63;
    int t = t0 + tl;
    if (t < NT) {
#pragma unroll
        for (int p = 0; p < 4; ++p) {
            int sl = (tid >> 6) + p * 4;
            const float* r = &sX[tl][sl * 6];
            size_t base = ((size_t)(s0 + sl) * 6) * NT + t;
            xT[base + 0 * NT] = r[0];
            xT[base + 1 * NT] = r[1];
            xT[base + 2 * NT] = r[2];
            xT[base + 3 * NT] = r[3];
            xT[base + 4 * NT] = r[4];
            xT[base + 5 * NT] = r[5];
        }
    }
}

// ---------------------------------------------------------------------------
// Kernel 1: per-site parameters, 4 sites per block — round-13 measured-good.
// ---------------------------------------------------------------------------
__global__ __launch_bounds__(256) void k_site(
    const float* __restrict__ xc, const float* __restrict__ W_fc, const float* __restrict__ b_fc,
    const float* __restrict__ W_r, const float* __restrict__ b_r,
    const float* __restrict__ W_g, const float* __restrict__ b_g,
    const float* __restrict__ b_kin,
    float* __restrict__ state2, float* __restrict__ params, float* __restrict__ wfir)
{
    int s0 = blockIdx.x * SSB, tid = threadIdx.x;
    __shared__ float sXc[SSB][NG];
    __shared__ float sG[SSB][HS];
    __shared__ float sPG[144][SSB];
    __shared__ float sPR[256][SSB];
    if (tid < SSB * NG) sXc[tid >> 5][tid & 31] = xc[(s0 + (tid >> 5)) * NG + (tid & 31)];
    __syncthreads();
    {
        float b = b_fc[tid];
        float a[SSB];
#pragma unroll
        for (int sl = 0; sl < SSB; ++sl) a[sl] = b;
#pragma unroll 8
        for (int g = 0; g < NG; ++g) {
            float w = W_fc[g * HS + tid];
#pragma unroll
            for (int sl = 0; sl < SSB; ++sl) a[sl] += sXc[sl][g] * w;
        }
        float bk = b_kin[tid];
#pragma unroll
        for (int sl = 0; sl < SSB; ++sl) {
            state2[(size_t)(s0 + sl) * HS + tid] = a[sl] + bk;
            sG[sl][tid] = fast_tanh(a[sl]);
        }
    }
    __syncthreads();
    {
        float b = b_r[tid];
        float r[SSB];
#pragma unroll
        for (int sl = 0; sl < SSB; ++sl) r[sl] = b;
#pragma unroll 8
        for (int u = 0; u < HS; ++u) {
            float w = W_r[u * 256 + tid];
#pragma unroll
            for (int sl = 0; sl < SSB; ++sl) r[sl] += sG[sl][u] * w;
        }
#pragma unroll
        for (int sl = 0; sl < SSB; ++sl) sPR[tid][sl] = r[sl];
    }
    if (tid < 144) {
        float b = b_g[tid];
        float gacc[SSB];
#pragma unroll
        for (int sl = 0; sl < SSB; ++sl) gacc[sl] = b;
#pragma unroll 8
        for (int u = 0; u < HS; ++u) {
            float w = W_g[u * 144 + tid];
#pragma unroll
            for (int sl = 0; sl < SSB; ++sl) gacc[sl] += sG[sl][u] * w;
        }
#pragma unroll
        for (int sl = 0; sl < SSB; ++sl) sPG[tid][sl] = gacc[sl];
    }
    __syncthreads();
    if (tid < SSB * NH) {
        int sl = tid >> 4, h = tid & 15;
        int s = s0 + sl;
        float m = -1e30f;
        for (int k = 0; k < NH; ++k) m = fmaxf(m, sPG[96 + k][sl]);
        float sum = 0.f;
        for (int k = 0; k < NH; ++k) sum += __expf(sPG[96 + k][sl] - m);
        float ga = __expf(sPG[96 + h][sl] - m) * fast_rcp(sum);
        float kp = fast_sigmoid(sPG[h][sl]);
        float ks = fast_sigmoid(sPG[16 + h][sl]);
        float kd = fast_sigmoid(sPG[32 + h][sl]);
        float gd = fast_sigmoid(sPG[48 + h][sl]);
        float glv = fast_sigmoid(sPG[64 + h][sl]) * 10.0f;
        float gl = glv * glv * glv;
        float qb = fmaxf(sPG[80 + h][sl], 0.f) * 0.1f;
        float gi = fminf(fmaxf(sPG[112 + h][sl] * (1.0f / 6.0f) + 0.5f, 0.f), 1.f) * 0.5f;
        float ge = fmaxf(sPG[128 + h][sl], 0.f);
        float* P = params + (size_t)s * 128;
        P[0 * 16 + h] = kp;  P[1 * 16 + h] = ks;  P[2 * 16 + h] = kd;  P[3 * 16 + h] = gd;
        P[4 * 16 + h] = gl;  P[5 * 16 + h] = qb;  P[6 * 16 + h] = gi;  P[7 * 16 + h] = ge;
        float loc = fast_sigmoid(sPR[h * 16 + 0][sl]) * 15.0f;
        float l[NR];
        float mm = -1e30f;
#pragma unroll
        for (int i = 0; i < NR; ++i) {
            float d = (float)i - loc;
            l[i] = sPR[h * 16 + 1 + i][sl] - d * d;
            mm = fmaxf(mm, l[i]);
        }
        float ssum = 0.f;
#pragma unroll
        for (int i = 0; i < NR; ++i) { l[i] = __expf(l[i] - mm); ssum += l[i]; }
        float r = fast_rcp(ssum) * ga;
#pragma unroll
        for (int i = 0; i < NR; ++i) wfir[(size_t)s * (NR * NH) + i * NH + h] = l[i] * r;
    }
}

// ---------------------------------------------------------------------------
// Kernel 2 (MFMA, split-K, packed-fp32, colsum trick) — round-8 exact,
// double-buffered sRed (measured 159.5-159.9 µs x4; FROZEN).
// ---------------------------------------------------------------------------
__global__ __launch_bounds__(256) void k_km(
    const float* __restrict__ xT, const float* __restrict__ state2,
    const float* __restrict__ W_kin, const float* __restrict__ W_kout,
    const float* __restrict__ b_kout, _Float16* __restrict__ kmh)
{
    const float Ck = 2.8853900817779268f;  // 2*log2(e)
    int s = blockIdx.x, tid = threadIdx.x;
    int wave = tid >> 6, lane = tid & 63;
    int r15 = lane & 15, kg = lane >> 4;

    f32x2 st[2][4], w0[2][4], w1[2][4], w2[2][4], w3[2][4];
    bhalf8 Bf[2];
    float csp = 0.f;
#pragma unroll
    for (int q = 0; q < 2; ++q) {
        int u0 = (2 * wave + q) * 32 + kg * 8;
#pragma unroll
        for (int e = 0; e < 4; ++e) {
            int u = u0 + 2 * e;
            st[q][e] = *(const f32x2*)(state2 + s * HS + u) * Ck;
            w0[q][e] = *(const f32x2*)(W_kin + 0 * HS + u) * Ck;
            w1[q][e] = *(const f32x2*)(W_kin + 1 * HS + u) * Ck;
            w2[q][e] = *(const f32x2*)(W_kin + 2 * HS + u) * Ck;
            w3[q][e] = *(const f32x2*)(W_kin + 3 * HS + u) * Ck;
            float wa = W_kout[(u)     * NH + r15];
            float wb = W_kout[(u + 1) * NH + r15];
            csp += wa + wb;
            Bf[q][2 * e]     = f2bf(-2.0f * wa);
            Bf[q][2 * e + 1] = f2bf(-2.0f * wb);
        }
    }
    __shared__ float sCS[4][4][16];
    sCS[wave][kg][r15] = csp;
    __syncthreads();
    float bk2 = b_kout[r15];
#pragma unroll
    for (int w = 0; w < 4; ++w)
#pragma unroll
        for (int k = 0; k < 4; ++k) bk2 += sCS[w][k][r15];

    const float* fpl = xT + ((size_t)s * 6 + 2) * NT;
    _Float16* kp = kmh + (size_t)s * NT * NH;

    __shared__ f32x4 sRed[2][4][4][64];

    for (int tg = 0; tg < 16; ++tg) {
        int buf = tg & 1;
#pragma unroll
        for (int tile = 0; tile < 4; ++tile) {
            int t = tg * 64 + tile * 16 + r15;
            int tcl = t < NT ? t : NT - 1;
            float f0 = fpl[tcl];
            float f1 = fpl[NT + tcl];
            float f2 = fpl[2 * NT + tcl];
            float f3 = fpl[3 * NT + tcl];
            f32x4 acc = {0.f, 0.f, 0.f, 0.f};
#pragma unroll
            for (int q = 0; q < 2; ++q) {
                bhalf8 A;
#pragma unroll
                for (int e = 0; e < 4; ++e) {
                    f32x2 p = st[q][e];
                    p += f0 * w0[q][e];
                    p += f1 * w1[q][e];
                    p += f2 * w2[q][e];
                    p += f3 * w3[q][e];
                    f32x2 ex = {__builtin_amdgcn_exp2f(p.x), __builtin_amdgcn_exp2f(p.y)};
                    f32x2 e1 = ex + 1.0f;
                    A[2 * e]     = f2bf(fast_rcp(e1.x));
                    A[2 * e + 1] = f2bf(fast_rcp(e1.y));
                }
                acc = __builtin_amdgcn_mfma_f32_16x16x32_bf16(A, Bf[q], acc, 0, 0, 0);
            }
            sRed[buf][tile][wave][lane] = acc;
        }
        __syncthreads();
        {
            f32x4 a0 = sRed[buf][wave][0][lane];
            f32x4 a1 = sRed[buf][wave][1][lane];
            f32x4 a2 = sRed[buf][wave][2][lane];
            f32x4 a3 = sRed[buf][wave][3][lane];
            f32x4 acc = (a0 + a1) + (a2 + a3);
            int tb = tg * 64 + wave * 16;
#pragma unroll
            for (int j = 0; j < 4; ++j) {
                int tt = tb + kg * 4 + j;
                if (tt < NT) kp[(size_t)tt * NH + r15] = (_Float16)__expf(acc[j] + bk2);
            }
        }
    }
}

// ---------------------------------------------------------------------------
// Kernel 3: sequential scan — round-4 direct-store version (measured best).
// ---------------------------------------------------------------------------
__global__ __launch_bounds__(128) void k_scan(
    const float* __restrict__ params, const float* __restrict__ xT,
    _Float16* __restrict__ kmh)
{
    int tid = threadIdx.x;
    int sl = tid >> 4, h = tid & 15;
    int S0 = blockIdx.x * SPB;
    __shared__ __align__(16) unsigned short sKmH[2][TC][128];
    __shared__ __align__(16) float sF[2][3][SPB][TC];

    const float* P = params + (size_t)(S0 + sl) * 128;
    float kp = P[h], ks = P[16 + h], kd = P[32 + h], gd = P[48 + h];
    float gl = P[64 + h], qb = P[80 + h], gi = P[96 + h], ge = P[112 + h];
    float gi1 = 1.f - gi, gd1 = 1.f - gd, kd1 = 1.f - kd;
    float Sf = 0.f, Ss = 0.f, Sd = 0.f;

    us4 vkm[10];
    float4 fP, fE, fT1, fT2;
    int fsite = tid / 10, ftcq = tid - fsite * 10;
    size_t fbase = ((size_t)(S0 + (fsite < SPB ? fsite : 0)) * 6) * NT + ftcq * 4;

    auto LOAD = [&](int t0) {
#pragma unroll
        for (int r = 0; r < 10; ++r) {
            int g = r * 128 + tid;
            int site = g / 160;
            int rem = g - site * 160;
            int tc = rem >> 2, h0 = (rem & 3) << 2;
            vkm[r] = *(const us4*)(kmh + (((size_t)(S0 + site) * NT + t0 + tc) * NH + h0));
        }
        if (tid < 80) {
            fP  = *(const float4*)(xT + fbase + t0);
            fE  = *(const float4*)(xT + fbase + (size_t)NT + t0);
            fT1 = *(const float4*)(xT + fbase + 2 * (size_t)NT + t0);
            fT2 = *(const float4*)(xT + fbase + 3 * (size_t)NT + t0);
        }
    };
    auto STORE_LDS = [&](int b) {
#pragma unroll
        for (int r = 0; r < 10; ++r) {
            int g = r * 128 + tid;
            int site = g / 160;
            int rem = g - site * 160;
            int tc = rem >> 2, h0 = (rem & 3) << 2;
            *(us4*)&sKmH[b][tc][site * 16 + h0] = vkm[r];
        }
        if (tid < 80) {
            float4 ps, pl;
            {
                float den = fmaxf(fT2.x - fT1.x, 1e-6f);
                float vL = fminf(fmaxf(fT2.x * fast_rcp(den), 0.f), 1.f);
                pl.x = fP.x * vL; ps.x = fP.x - pl.x;
            }
            {
                float den = fmaxf(fT2.y - fT1.y, 1e-6f);
                float vL = fminf(fmaxf(fT2.y * fast_rcp(den), 0.f), 1.f);
                pl.y = fP.y * vL; ps.y = fP.y - pl.y;
            }
            {
                float den = fmaxf(fT2.z - fT1.z, 1e-6f);
                float vL = fminf(fmaxf(fT2.z * fast_rcp(den), 0.f), 1.f);
                pl.z = fP.z * vL; ps.z = fP.z - pl.z;
            }
            {
                float den = fmaxf(fT2.w - fT1.w, 1e-6f);
                float vL = fminf(fmaxf(fT2.w * fast_rcp(den), 0.f), 1.f);
                pl.w = fP.w * vL; ps.w = fP.w - pl.w;
            }
            *(float4*)&sF[b][0][fsite][ftcq * 4] = ps;
            *(float4*)&sF[b][1][fsite][ftcq * 4] = pl;
            *(float4*)&sF[b][2][fsite][ftcq * 4] = fE;
        }
    };

    size_t qbase = ((size_t)(S0 + sl) * NT) * NH + h;

    LOAD(0);
    STORE_LDS(0);
    __syncthreads();
    for (int c = 0; c < NCH; ++c) {
        int b = c & 1;
        if (c + 1 < NCH) LOAD((c + 1) * TC);
        int t0 = c * TC;
#pragma unroll 8
        for (int tc = 0; tc < TC; ++tc) {
            float ps = sF[b][0][sl][tc], pl = sF[b][1][sl][tc], ev = sF[b][2][sl][tc];
            float kmv = h2f(sKmH[b][tc][tid]);
            Sf += ps;
            float qf = fminf(Sf, kmv);
            Sf -= qf;
            float Pin = pl + qf;
            float H = fmaxf(Ss + Pin * gi1 - ev * ge, 0.f);
            float qp = fmaxf(H - gl, 0.f) * kp;
            float qo = fminf(H, gl) * ks;
            Ss = H - qp - qo;
            float D = Sd + Pin * gi + qo * gd;
            float qd = D * kd + qb;
            Sd = D * kd1;
            kmh[qbase + (size_t)(t0 + tc) * NH] = (_Float16)(qp + qo * gd1 + qd);
        }
        if (c + 1 < NCH) {
            STORE_LDS((c + 1) & 1);
            __syncthreads();
        }
    }
}

// ---------------------------------------------------------------------------
// Kernel 4: register-window FIR, h-loop NOT unrolled (the spill fix).
// fp16 sQ (33.5 KB -> 4 blocks/CU); thread owns 4 taus; per h:
// 5x ds_read_b64 window + broadcast weights + 60 FMA. Same accumulation
// order (h outer, i inner) as the per-tau version -> bit-identical.
// ---------------------------------------------------------------------------
__global__ __launch_bounds__(256) void k_fir(
    const _Float16* __restrict__ kmh, const float* __restrict__ wfir,
    float* __restrict__ out)
{
    int s = blockIdx.x, tid = threadIdx.x;
    __shared__ unsigned short sQ[NH][QROW];  // fp16 bits, 33.5 KB
    __shared__ float sW[NH][16];             // [h][i], padded to 16
    // zero tail t in [NT, QROW)
    for (int idx = tid; idx < NH * (QROW - NT); idx += 256) {
        int h = idx / (QROW - NT), j = idx - h * (QROW - NT);
        sQ[h][NT + j] = 0;
    }
    // stage qTot[s] transposed (fp16 stays fp16)
    const us8* src = (const us8*)(kmh + (size_t)s * NT * NH);
    for (int g = tid; g < NT * NH / 8; g += 256) {
        us8 v = src[g];
        int t = g >> 1, h0 = (g & 1) << 3;
#pragma unroll
        for (int e = 0; e < 8; ++e) sQ[h0 + e][t] = v[e];
    }
    if (tid < NR * NH) sW[tid & 15][tid >> 4] = wfir[(size_t)s * NR * NH + tid];
    __syncthreads();

    int tau0 = tid * 4;
    if (tau0 < LOUT) {
        float a0 = 0.f, a1 = 0.f, a2 = 0.f, a3 = 0.f;
#pragma unroll 1
        for (int h = 0; h < NH; ++h) {
            float q[20];
#pragma unroll
            for (int r = 0; r < 5; ++r) {
                us4 v = *(const us4*)&sQ[h][tau0 + 4 * r];
                q[4 * r + 0] = h2f(v[0]);
                q[4 * r + 1] = h2f(v[1]);
                q[4 * r + 2] = h2f(v[2]);
                q[4 * r + 3] = h2f(v[3]);
            }
#pragma unroll
            for (int i = 0; i < NR; ++i) {
                float w = sW[h][i];
                a0 += q[i] * w;
                a1 += q[i + 1] * w;
                a2 += q[i + 2] * w;
                a3 += q[i + 3] * w;
            }
        }
        out[(size_t)(tau0 + 0) * NS + s] = a0;
        if (tau0 + 1 < LOUT) out[(size_t)(tau0 + 1) * NS + s] = a1;
        if (tau0 + 2 < LOUT) out[(size_t)(tau0 + 2) * NS + s] = a2;
        if (tau0 + 3 < LOUT) out[(size_t)(tau0 + 3) * NS + s] = a3;
    }
}

// ---------------------------------------------------------------------------
extern "C" void kernel_launch(void* const* d_in, const int* in_sizes, int n_in,
                              void* d_out, int out_size, void* d_ws, size_t ws_size,
                              hipStream_t stream) {
    const float* x      = (const float*)d_in[0];
    const float* xc     = (const float*)d_in[1];
    const float* W_fc   = (const float*)d_in[2];
    const float* b_fc   = (const float*)d_in[3];
    const float* W_r    = (const float*)d_in[4];
    const float* b_r    = (const float*)d_in[5];
    const float* W_g    = (const float*)d_in[6];
    const float* b_g    = (const float*)d_in[7];
    const float* W_kin  = (const float*)d_in[8];
    const float* b_kin  = (const float*)d_in[9];
    const float* W_kout = (const float*)d_in[10];
    const float* b_kout = (const float*)d_in[11];
    float* out = (float*)d_out;

    float* ws     = (float*)d_ws;
    float* state2 = ws;                             // NS*HS
    float* params = state2 + (size_t)NS * HS;       // NS*128
    float* wfir   = params + (size_t)NS * 128;      // NS*NR*NH
    float* xT     = wfir + (size_t)NS * NR * NH;    // NS*6*NT
    _Float16* kmh = (_Float16*)(xT + (size_t)NS * 6 * NT);   // NS*NT*NH fp16

    k_prep<<<dim3(NS / 16, (NT + 63) / 64), 256, 0, stream>>>(x, xT);
    k_site<<<NS / SSB, 256, 0, stream>>>(xc, W_fc, b_fc, W_r, b_r, W_g, b_g, b_kin,
                                         state2, params, wfir);
    k_km<<<NS, 256, 0, stream>>>(xT, state2, W_kin, W_kout, b_kout, kmh);
    k_scan<<<NS / SPB, 128, 0, stream>>>(params, xT, kmh);
    k_fir<<<NS, 256, 0, stream>>>(kmh, wfir, out);
}